// Round 4
// baseline (456.174 us; speedup 1.0000x reference)
//
#include <hip/hip_runtime.h>
#include <math.h>

#define L_SZ 8192
#define H_SZ 512
#define P_SZ 1024

using bf16x8 = __attribute__((ext_vector_type(8))) short;
using f32x4  = __attribute__((ext_vector_type(4))) float;
using f32x2  = __attribute__((ext_vector_type(2))) float;
using us4    = __attribute__((ext_vector_type(4))) unsigned short;

__device__ __forceinline__ unsigned short f2bf_rtn(float f) {
    unsigned int x = __builtin_bit_cast(unsigned int, f);
    x += 0x7fffu + ((x >> 16) & 1u);
    return (unsigned short)(x >> 16);
}
__device__ __forceinline__ unsigned int pack_bf2(float lo, float hi) {
    return (unsigned int)f2bf_rtn(lo) | ((unsigned int)f2bf_rtn(hi) << 16);
}
__device__ __forceinline__ float fast_tanh(float x) {
    float e = __builtin_amdgcn_exp2f(x * 2.8853900817779268f); // 2*log2(e)
    return 1.0f - 2.0f * __builtin_amdgcn_rcpf(e + 1.0f);
}
__device__ __forceinline__ float fast_sigmoid(float x) {
    float e = __builtin_amdgcn_exp2f(-x * 1.4426950408889634f);
    return __builtin_amdgcn_rcpf(1.0f + e);
}

__global__ __launch_bounds__(256) void cvt_f32_bf16(const float* __restrict__ in,
                                                    unsigned short* __restrict__ out,
                                                    int n4) {
    int i = blockIdx.x * 256 + threadIdx.x;
    if (i < n4) {
        float4 v = reinterpret_cast<const float4*>(in)[i];
        us4 o;
        o.x = f2bf_rtn(v.x); o.y = f2bf_rtn(v.y);
        o.z = f2bf_rtn(v.z); o.w = f2bf_rtn(v.w);
        reinterpret_cast<us4*>(out)[i] = o;
    }
}

// C'[h][p] = C[h][p] / W[p]  (bf16 out) — folds the delta->y scale into GEMM2
__global__ __launch_bounds__(256) void cvt_scale_bf16(const float* __restrict__ in,
                                                      const float* __restrict__ Wd,
                                                      unsigned short* __restrict__ out,
                                                      int n4) {
    int i = blockIdx.x * 256 + threadIdx.x;
    if (i < n4) {
        float4 v = reinterpret_cast<const float4*>(in)[i];
        int p0 = (i * 4) & (P_SZ - 1);
        float4 wv = *reinterpret_cast<const float4*>(&Wd[p0]);
        us4 o;
        o.x = f2bf_rtn(v.x / wv.x); o.y = f2bf_rtn(v.y / wv.y);
        o.z = f2bf_rtn(v.z / wv.z); o.w = f2bf_rtn(v.w / wv.w);
        reinterpret_cast<us4*>(out)[i] = o;
    }
}

__device__ __forceinline__ void gload_lds16(const void* g, void* l) {
    __builtin_amdgcn_global_load_lds(
        (const __attribute__((address_space(1))) unsigned int*)g,
        (__attribute__((address_space(3))) unsigned int*)l, 16, 0, 0);
}

#define BT  128
#define BKK 32

// NT bf16 MFMA GEMM.
// MODE 0: Cout[m][n] = acc + Dvec[n]*U[m][n]   (GEMM2)
// MODE 1: Q-coefficient epilogue (GEMM1): a = acc + b[n]; f = tanh(a);
//         emit packed bf16 {Q0,Q1,Q2,Q3} per (timestep, channel)
template <int MODE>
__global__ __launch_bounds__(256) void gemm_nt_bf16(
    const unsigned short* __restrict__ A,   // (M,K) bf16 row-major
    const unsigned short* __restrict__ Bm,  // (N,K) bf16 row-major
    float* __restrict__ Cout, int M, int N, int K,
    const float* __restrict__ Dvec, const float* __restrict__ U,
    uint4* __restrict__ Qpk,
    const float* __restrict__ Wd, const float* __restrict__ bv,
    const float* __restrict__ cvec, const float* __restrict__ alpha_p)
{
    __shared__ __align__(16) unsigned short As[BT * BKK];
    __shared__ __align__(16) unsigned short Bs[BT * BKK];
    const int tid  = threadIdx.x;
    const int wave = tid >> 6;
    const int lane = tid & 63;
    const int bm = blockIdx.x * BT;
    const int bn = blockIdx.y * BT;
    const int wm = (wave >> 1) * 64;
    const int wn = (wave & 1) * 64;

    const int srow = wave * 16 + (lane >> 2);
    const int scol = (lane & 3) * 8;
    const unsigned short* aptr0 = A  + (size_t)(bm + srow)      * K + scol;
    const unsigned short* aptr1 = A  + (size_t)(bm + 64 + srow) * K + scol;
    const unsigned short* bptr0 = Bm + (size_t)(bn + srow)      * K + scol;
    const unsigned short* bptr1 = Bm + (size_t)(bn + 64 + srow) * K + scol;
    unsigned short* asl0 = As + wave * 512;
    unsigned short* asl1 = As + 2048 + wave * 512;
    unsigned short* bsl0 = Bs + wave * 512;
    unsigned short* bsl1 = Bs + 2048 + wave * 512;

    const int frow = lane & 15;
    const int fk   = (lane >> 4) * 8;

    f32x4 acc[4][4];
    #pragma unroll
    for (int i = 0; i < 4; ++i)
        #pragma unroll
        for (int j = 0; j < 4; ++j)
            acc[i][j] = (f32x4){0.f, 0.f, 0.f, 0.f};

    for (int k0 = 0; k0 < K; k0 += BKK) {
        __syncthreads();
        gload_lds16(aptr0 + k0, asl0);
        gload_lds16(aptr1 + k0, asl1);
        gload_lds16(bptr0 + k0, bsl0);
        gload_lds16(bptr1 + k0, bsl1);
        __syncthreads();
        bf16x8 a[4], b[4];
        #pragma unroll
        for (int i = 0; i < 4; ++i) {
            a[i] = *reinterpret_cast<const bf16x8*>(&As[(wm + i * 16 + frow) * BKK + fk]);
            b[i] = *reinterpret_cast<const bf16x8*>(&Bs[(wn + i * 16 + frow) * BKK + fk]);
        }
        #pragma unroll
        for (int i = 0; i < 4; ++i)
            #pragma unroll
            for (int j = 0; j < 4; ++j)
                acc[i][j] = __builtin_amdgcn_mfma_f32_16x16x32_bf16(a[i], b[j], acc[i][j], 0, 0, 0);
    }

    const int crow = bm + wm + (lane >> 4) * 4;   // multiple of 4
    const int ccol = bn + wn + (lane & 15);

    if constexpr (MODE == 0) {
        #pragma unroll
        for (int i = 0; i < 4; ++i)
            #pragma unroll
            for (int j = 0; j < 4; ++j)
                #pragma unroll
                for (int r = 0; r < 4; ++r) {
                    int row = crow + i * 16 + r;
                    int col = ccol + j * 16;
                    float v = acc[i][j][r];
                    v = fmaf(Dvec[col], U[(size_t)row * N + col], v);
                    Cout[(size_t)row * N + col] = v;
                }
    } else {
        const float alpha = alpha_p[0];
        #pragma unroll
        for (int j = 0; j < 4; ++j) {
            const int col = ccol + j * 16;
            const float ce  = fast_sigmoid(fast_sigmoid(cvec[col]));
            const float ce3 = ce * (1.0f / 3.0f);
            const float alW = alpha / Wd[col];
            const float bb  = bv[col];
            #pragma unroll
            for (int i = 0; i < 4; ++i) {
                unsigned int w01[4], w23[4];
                #pragma unroll
                for (int r = 0; r < 4; ++r) {
                    float a  = acc[i][j][r] + bb;
                    float f  = fast_tanh(a);
                    float p1 = fmaf(-f, f, 1.0f);          // 1 - f^2
                    float q0 = ce * f;
                    float q1 = fmaf(ce, p1, alW);
                    float q2 = -q0 * p1;                    // -ce*f*(1-f^2)
                    float t3 = fmaf(-3.0f * f, f, 1.0f);    // 1 - 3f^2
                    float q3 = -ce3 * p1 * t3;              // -(ce/3)(1-f^2)(1-3f^2)
                    w01[r] = pack_bf2(q0, q1);
                    w23[r] = pack_bf2(q2, q3);
                }
                const int row0 = crow + i * 16;             // even
                size_t tp0 = (size_t)(row0 >> 1) * P_SZ + col;
                Qpk[tp0]        = make_uint4(w01[0], w23[0], w01[1], w23[1]);
                Qpk[tp0 + P_SZ] = make_uint4(w01[2], w23[2], w01[3], w23[3]);
            }
        }
    }
}

// ---------------- scan ----------------
// Per 16-step block: freeze d at block start -> 16 independent cubic evals
// (packed fp32 pairs), then a 3-op/step sequential state update.
// LDS-DMA 3-slot pipeline with counted vmcnt keeps Qpk loads off the chain.
//   g_j  = Q0_j + Q1_j*d0 + Q2_j*d0^2 + Q3_j*d0^3
//   zeta_{j+1} = zeta_j + cz*g_j          (cz = -W*st^2)
//   d_{j+1}    = d_j + zeta_j + ch*g_j    (ch = cz/2)
// ys[t] = d_{t+1}/W; store bf16(d), 1/W folded into C for GEMM2.

#define SD_T 16
#define NBLK (L_SZ / SD_T)   // 512

__global__ __launch_bounds__(64, 1) void scan_kernel(
    const uint4* __restrict__ Qpk,       // [L/2][P] packed {Q0Q1,Q2Q3} x2 steps
    unsigned short* __restrict__ ysb,    // [L][P] bf16 (W*y)
    const float* __restrict__ Wd, const float* __restrict__ step_p)
{
    __shared__ __align__(16) uint4 qlds[3 * 8 * 64];   // 3 slots x 8 KB
    const int lane = threadIdx.x;
    const int p = blockIdx.x * 64 + lane;
    const float W  = Wd[p];
    const float st = step_p[0];
    const float cz = -W * st * st;
    const float ch = 0.5f * cz;
    float d = 0.f, zeta = 0.f;

    const uint4* gq = Qpk + p;
    #pragma unroll
    for (int pb = 0; pb < 3; ++pb)
        #pragma unroll
        for (int r = 0; r < 8; ++r)
            gload_lds16(gq + (size_t)(pb * 8 + r) * P_SZ,
                        (char*)qlds + pb * 8192 + r * 1024);
    gq += 3 * 8 * P_SZ;

    int slot = 0;
    unsigned yoff = (unsigned)p;

    for (int blk = 0; blk < NBLK; ++blk) {
        // counted waits: N = vmem ops issued after this block's 8 loads
        if (blk == 0)            asm volatile("s_waitcnt vmcnt(16)" ::: "memory");
        else if (blk == 1)       asm volatile("s_waitcnt vmcnt(32)" ::: "memory");
        else if (blk < NBLK - 2) asm volatile("s_waitcnt vmcnt(48)" ::: "memory");
        else                     asm volatile("s_waitcnt vmcnt(32)" ::: "memory");

        const uint4* lsl = qlds + slot * 512 + lane;
        uint4 q[8];
        #pragma unroll
        for (int r = 0; r < 8; ++r) q[r] = lsl[r * 64];

        const f32x2 d0v = {d, d};
        float gs[SD_T];
        #pragma unroll
        for (int k = 0; k < 8; ++k) {
            uint4 w = q[k];
            f32x2 Q1 = {__builtin_bit_cast(float, w.x), __builtin_bit_cast(float, w.z)};
            f32x2 Q0 = {__builtin_bit_cast(float, w.x << 16), __builtin_bit_cast(float, w.z << 16)};
            f32x2 Q3 = {__builtin_bit_cast(float, w.y), __builtin_bit_cast(float, w.w)};
            f32x2 Q2 = {__builtin_bit_cast(float, w.y << 16), __builtin_bit_cast(float, w.w << 16)};
            f32x2 h = __builtin_elementwise_fma(Q3, d0v, Q2);
            h = __builtin_elementwise_fma(h, d0v, Q1);
            h = __builtin_elementwise_fma(h, d0v, Q0);
            gs[2 * k]     = h.x;
            gs[2 * k + 1] = h.y;
        }
        #pragma unroll
        for (int j = 0; j < SD_T; ++j) {
            float t = fmaf(ch, gs[j], zeta);
            d += t;
            zeta = fmaf(cz, gs[j], zeta);
            unsigned bits = __builtin_bit_cast(unsigned, d) + 0x8000u;
            ysb[yoff + (unsigned)j * P_SZ] = (unsigned short)(bits >> 16);
        }
        yoff += SD_T * P_SZ;

        asm volatile("s_waitcnt lgkmcnt(0)" ::: "memory");  // ds_reads drained
        if (blk + 3 < NBLK) {
            #pragma unroll
            for (int r = 0; r < 8; ++r)
                gload_lds16(gq + (size_t)r * P_SZ,
                            (char*)qlds + slot * 8192 + r * 1024);
            gq += 8 * P_SZ;
        }
        slot = (slot == 2) ? 0 : slot + 1;
    }
}

extern "C" void kernel_launch(void* const* d_in, const int* in_sizes, int n_in,
                              void* d_out, int out_size, void* d_ws, size_t ws_size,
                              hipStream_t stream) {
    const float* u     = (const float*)d_in[0];  // (L,H)
    const float* B     = (const float*)d_in[1];  // (P,H)
    const float* C     = (const float*)d_in[2];  // (H,P)
    const float* D     = (const float*)d_in[3];  // (H,)
    const float* W     = (const float*)d_in[4];  // (P,)
    const float* b     = (const float*)d_in[5];  // (P,)
    const float* c     = (const float*)d_in[6];  // (P,)
    const float* alpha = (const float*)d_in[7];  // (1,)
    const float* step  = (const float*)d_in[8];  // (1,)
    float* out = (float*)d_out;                  // (L,H)

    char* ws = (char*)d_ws;
    uint4*          Qpk = (uint4*)ws;                                  // 64 MiB
    unsigned short* ysb = (unsigned short*)(ws + ((size_t)64 << 20));  // 16 MiB
    unsigned short* ub  = (unsigned short*)(ws + ((size_t)80 << 20));  // 8 MiB
    unsigned short* Bb  = (unsigned short*)(ws + ((size_t)88 << 20));  // 1 MiB
    unsigned short* Cb  = (unsigned short*)(ws + ((size_t)89 << 20));  // 1 MiB

    cvt_f32_bf16<<<dim3(L_SZ * H_SZ / 4 / 256), dim3(256), 0, stream>>>(u, ub, L_SZ * H_SZ / 4);
    cvt_f32_bf16<<<dim3(P_SZ * H_SZ / 4 / 256), dim3(256), 0, stream>>>(B, Bb, P_SZ * H_SZ / 4);
    cvt_scale_bf16<<<dim3(H_SZ * P_SZ / 4 / 256), dim3(256), 0, stream>>>(C, W, Cb, H_SZ * P_SZ / 4);

    // GEMM1 + fused tanh/Q-coefficient epilogue: (u @ B^T) -> Qpk
    gemm_nt_bf16<1><<<dim3(L_SZ / BT, P_SZ / BT), dim3(256), 0, stream>>>(
        ub, Bb, nullptr, L_SZ, P_SZ, H_SZ, nullptr, nullptr,
        Qpk, W, b, c, alpha);

    // sequential leapfrog scan (frozen-d cubic blocks), emits bf16 del = W*y
    scan_kernel<<<dim3(P_SZ / 64), dim3(64), 0, stream>>>(Qpk, ysb, W, step);

    // GEMM2: out = ys @ (C/W)^T + D .* u
    gemm_nt_bf16<0><<<dim3(L_SZ / BT, H_SZ / BT), dim3(256), 0, stream>>>(
        ysb, Cb, out, L_SZ, H_SZ, P_SZ, D, u,
        nullptr, nullptr, nullptr, nullptr, nullptr);
}

// Round 5
// 123.501 us; speedup vs baseline: 3.6937x; 3.6937x over previous
//
#include <hip/hip_runtime.h>
#include <math.h>

#define L_SZ 8192
#define H_SZ 512
#define P_SZ 1024

using bf16x8 = __attribute__((ext_vector_type(8))) short;
using f32x4  = __attribute__((ext_vector_type(4))) float;
using us4    = __attribute__((ext_vector_type(4))) unsigned short;

__device__ __forceinline__ unsigned short f2bf_rtn(float f) {
    unsigned int x = __builtin_bit_cast(unsigned int, f);
    x += 0x7fffu + ((x >> 16) & 1u);
    return (unsigned short)(x >> 16);
}
__device__ __forceinline__ unsigned int pack_bf2(float lo, float hi) {
    return (unsigned int)f2bf_rtn(lo) | ((unsigned int)f2bf_rtn(hi) << 16);
}
__device__ __forceinline__ float fast_tanh(float x) {
    float e = __builtin_amdgcn_exp2f(x * 2.8853900817779268f); // 2*log2(e)
    return 1.0f - 2.0f * __builtin_amdgcn_rcpf(e + 1.0f);
}
__device__ __forceinline__ float fast_sigmoid(float x) {
    float e = __builtin_amdgcn_exp2f(-x * 1.4426950408889634f);
    return __builtin_amdgcn_rcpf(1.0f + e);
}

__global__ __launch_bounds__(256) void cvt_f32_bf16(const float* __restrict__ in,
                                                    unsigned short* __restrict__ out,
                                                    int n4) {
    int i = blockIdx.x * 256 + threadIdx.x;
    if (i < n4) {
        float4 v = reinterpret_cast<const float4*>(in)[i];
        us4 o;
        o.x = f2bf_rtn(v.x); o.y = f2bf_rtn(v.y);
        o.z = f2bf_rtn(v.z); o.w = f2bf_rtn(v.w);
        reinterpret_cast<us4*>(out)[i] = o;
    }
}

// C'[h][p] = C[h][p] / W[p]  (bf16 out) — folds the delta->y scale into GEMM2
__global__ __launch_bounds__(256) void cvt_scale_bf16(const float* __restrict__ in,
                                                      const float* __restrict__ Wd,
                                                      unsigned short* __restrict__ out,
                                                      int n4) {
    int i = blockIdx.x * 256 + threadIdx.x;
    if (i < n4) {
        float4 v = reinterpret_cast<const float4*>(in)[i];
        int p0 = (i * 4) & (P_SZ - 1);
        float4 wv = *reinterpret_cast<const float4*>(&Wd[p0]);
        us4 o;
        o.x = f2bf_rtn(v.x / wv.x); o.y = f2bf_rtn(v.y / wv.y);
        o.z = f2bf_rtn(v.z / wv.z); o.w = f2bf_rtn(v.w / wv.w);
        reinterpret_cast<us4*>(out)[i] = o;
    }
}

__device__ __forceinline__ void gload_lds16(const void* g, void* l) {
    __builtin_amdgcn_global_load_lds(
        (const __attribute__((address_space(1))) unsigned int*)g,
        (__attribute__((address_space(3))) unsigned int*)l, 16, 0, 0);
}

#define BT  128
#define BKK 32

// NT bf16 MFMA GEMM.
// MODE 0: Cout[m][n] = acc + Dvec[n]*U[m][n]   (GEMM2)
// MODE 1: Q-coefficient epilogue (GEMM1): a = acc + b[n]; f = tanh(a);
//         emit packed bf16 {Q0,Q1,Q2,Q3} per (timestep, channel)
template <int MODE>
__global__ __launch_bounds__(256) void gemm_nt_bf16(
    const unsigned short* __restrict__ A,   // (M,K) bf16 row-major
    const unsigned short* __restrict__ Bm,  // (N,K) bf16 row-major
    float* __restrict__ Cout, int M, int N, int K,
    const float* __restrict__ Dvec, const float* __restrict__ U,
    uint4* __restrict__ Qpk,
    const float* __restrict__ Wd, const float* __restrict__ bv,
    const float* __restrict__ cvec, const float* __restrict__ alpha_p)
{
    __shared__ __align__(16) unsigned short As[BT * BKK];
    __shared__ __align__(16) unsigned short Bs[BT * BKK];
    const int tid  = threadIdx.x;
    const int wave = tid >> 6;
    const int lane = tid & 63;
    const int bm = blockIdx.x * BT;
    const int bn = blockIdx.y * BT;
    const int wm = (wave >> 1) * 64;
    const int wn = (wave & 1) * 64;

    const int srow = wave * 16 + (lane >> 2);
    const int scol = (lane & 3) * 8;
    const unsigned short* aptr0 = A  + (size_t)(bm + srow)      * K + scol;
    const unsigned short* aptr1 = A  + (size_t)(bm + 64 + srow) * K + scol;
    const unsigned short* bptr0 = Bm + (size_t)(bn + srow)      * K + scol;
    const unsigned short* bptr1 = Bm + (size_t)(bn + 64 + srow) * K + scol;
    unsigned short* asl0 = As + wave * 512;
    unsigned short* asl1 = As + 2048 + wave * 512;
    unsigned short* bsl0 = Bs + wave * 512;
    unsigned short* bsl1 = Bs + 2048 + wave * 512;

    const int frow = lane & 15;
    const int fk   = (lane >> 4) * 8;

    f32x4 acc[4][4];
    #pragma unroll
    for (int i = 0; i < 4; ++i)
        #pragma unroll
        for (int j = 0; j < 4; ++j)
            acc[i][j] = (f32x4){0.f, 0.f, 0.f, 0.f};

    for (int k0 = 0; k0 < K; k0 += BKK) {
        __syncthreads();
        gload_lds16(aptr0 + k0, asl0);
        gload_lds16(aptr1 + k0, asl1);
        gload_lds16(bptr0 + k0, bsl0);
        gload_lds16(bptr1 + k0, bsl1);
        __syncthreads();
        bf16x8 a[4], b[4];
        #pragma unroll
        for (int i = 0; i < 4; ++i) {
            a[i] = *reinterpret_cast<const bf16x8*>(&As[(wm + i * 16 + frow) * BKK + fk]);
            b[i] = *reinterpret_cast<const bf16x8*>(&Bs[(wn + i * 16 + frow) * BKK + fk]);
        }
        #pragma unroll
        for (int i = 0; i < 4; ++i)
            #pragma unroll
            for (int j = 0; j < 4; ++j)
                acc[i][j] = __builtin_amdgcn_mfma_f32_16x16x32_bf16(a[i], b[j], acc[i][j], 0, 0, 0);
    }

    const int crow = bm + wm + (lane >> 4) * 4;   // multiple of 4
    const int ccol = bn + wn + (lane & 15);

    if constexpr (MODE == 0) {
        #pragma unroll
        for (int i = 0; i < 4; ++i)
            #pragma unroll
            for (int j = 0; j < 4; ++j)
                #pragma unroll
                for (int r = 0; r < 4; ++r) {
                    int row = crow + i * 16 + r;
                    int col = ccol + j * 16;
                    float v = acc[i][j][r];
                    v = fmaf(Dvec[col], U[(size_t)row * N + col], v);
                    Cout[(size_t)row * N + col] = v;
                }
    } else {
        const float alpha = alpha_p[0];
        #pragma unroll
        for (int j = 0; j < 4; ++j) {
            const int col = ccol + j * 16;
            const float ce  = fast_sigmoid(fast_sigmoid(cvec[col]));
            const float ce3 = ce * (1.0f / 3.0f);
            const float alW = alpha / Wd[col];
            const float bb  = bv[col];
            #pragma unroll
            for (int i = 0; i < 4; ++i) {
                unsigned int w01[4], w23[4];
                #pragma unroll
                for (int r = 0; r < 4; ++r) {
                    float a  = acc[i][j][r] + bb;
                    float f  = fast_tanh(a);
                    float p1 = fmaf(-f, f, 1.0f);          // 1 - f^2
                    float q0 = ce * f;
                    float q1 = fmaf(ce, p1, alW);
                    float q2 = -q0 * p1;                    // -ce*f*(1-f^2)
                    float t3 = fmaf(-3.0f * f, f, 1.0f);    // 1 - 3f^2
                    float q3 = -ce3 * p1 * t3;              // -(ce/3)(1-f^2)(1-3f^2)
                    w01[r] = pack_bf2(q0, q1);
                    w23[r] = pack_bf2(q2, q3);
                }
                const int row0 = crow + i * 16;             // even
                size_t tp0 = (size_t)(row0 >> 1) * P_SZ + col;
                Qpk[tp0]        = make_uint4(w01[0], w23[0], w01[1], w23[1]);
                Qpk[tp0 + P_SZ] = make_uint4(w01[2], w23[2], w01[3], w23[3]);
            }
        }
    }
}

// ---------------- Phase A: coarse sequential scan (512 Verlet steps) -------
// One coarse step integrates one 16-fine-step block with g frozen at the
// block-start coefficients:  d' = d + 16*zeta + 128*cz*g(d)
//                            zeta' = zeta + 8*cz*(g_prev + g)   (trapezoid)
// Emits the (d, zeta) state at every block start -> states[512][1024].
// Qpk rows for coarse step k: row 8k (steps 16k,16k+1 packed; use 16k).

#define CH_A 64                   // coarse steps per LDS chunk
#define NCH  (512 / CH_A)         // 8 chunks

__global__ __launch_bounds__(64, 1) void scan_coarse(
    const uint4* __restrict__ Qpk, float2* __restrict__ states,
    const float* __restrict__ Wd, const float* __restrict__ step_p)
{
    __shared__ __align__(16) uint4 qlds[2][CH_A * 64];   // 2 x 64 KB
    const int lane = threadIdx.x;
    const int p = blockIdx.x * 64 + lane;
    const float W  = Wd[p];
    const float st = step_p[0];
    const float cz    = -W * st * st;
    const float cz8   = 8.0f * cz;
    const float cz128 = 128.0f * cz;

    const uint4* gq = Qpk + p;    // coarse step k -> element (8k*P + p)

    // prologue: DMA chunk 0
    for (int r = 0; r < CH_A; ++r)
        gload_lds16(gq + (size_t)r * 8 * P_SZ, (char*)&qlds[0][0] + r * 16 * 64);

    float d = 0.f, zeta = 0.f, gprev = 0.f;

    for (int c = 0; c < NCH; ++c) {
        asm volatile("s_waitcnt vmcnt(0)" ::: "memory");   // chunk c resident
        if (c + 1 < NCH) {                                 // DMA chunk c+1
            const uint4* gc = gq + (size_t)(c + 1) * CH_A * 8 * P_SZ;
            for (int r = 0; r < CH_A; ++r)
                gload_lds16(gc + (size_t)r * 8 * P_SZ,
                            (char*)&qlds[(c + 1) & 1][0] + r * 16 * 64);
        }
        const uint4* lq = &qlds[c & 1][lane];
        for (int j = 0; j < CH_A; ++j) {
            uint4 w = lq[j * 64];
            float Q0 = __builtin_bit_cast(float, w.x << 16);
            float Q1 = __builtin_bit_cast(float, w.x);
            float Q2 = __builtin_bit_cast(float, w.y << 16);
            float Q3 = __builtin_bit_cast(float, w.y);
            float h = fmaf(Q3, d, Q2);
            h = fmaf(h, d, Q1);
            float g = fmaf(h, d, Q0);
            zeta = fmaf(cz8, gprev + g, zeta);   // k=0: adds 8cz*g0 ~ 4e-10, ok
            states[(size_t)(c * CH_A + j) * P_SZ + p] = make_float2(d, zeta);
            d = fmaf(cz128, g, fmaf(16.0f, zeta, d));
            gprev = g;
        }
    }
}

// ---------------- Phase B: parallel fine scan (exact cubic recurrence) -----
// 512 time-blocks x 1024 channels, each runs 16 exact steps from the coarse
// state:  g = Q0+Q1*d+Q2*d^2+Q3*d^3; t = ch*g+zeta; d += t; zeta += cz*g.

__global__ __launch_bounds__(256) void scan_fine(
    const uint4* __restrict__ Qpk, const float2* __restrict__ states,
    unsigned short* __restrict__ ysb,
    const float* __restrict__ Wd, const float* __restrict__ step_p)
{
    const int p  = blockIdx.y * 256 + threadIdx.x;
    const int bk = blockIdx.x;                    // time-block 0..511
    const float W  = Wd[p];
    const float st = step_p[0];
    const float cz = -W * st * st;
    const float ch = 0.5f * cz;

    float2 s = states[(size_t)bk * P_SZ + p];
    float d = s.x, zeta = s.y;

    uint4 q[8];
    #pragma unroll
    for (int r = 0; r < 8; ++r)
        q[r] = Qpk[(size_t)(bk * 8 + r) * P_SZ + p];

    unsigned short yo[16];
    #pragma unroll
    for (int r = 0; r < 8; ++r) {
        #pragma unroll
        for (int half = 0; half < 2; ++half) {
            unsigned int w01 = half ? q[r].z : q[r].x;
            unsigned int w23 = half ? q[r].w : q[r].y;
            float Q0 = __builtin_bit_cast(float, w01 << 16);
            float Q1 = __builtin_bit_cast(float, w01);
            float Q2 = __builtin_bit_cast(float, w23 << 16);
            float Q3 = __builtin_bit_cast(float, w23);
            float h = fmaf(Q3, d, Q2);
            h = fmaf(h, d, Q1);
            float g = fmaf(h, d, Q0);
            float t = fmaf(ch, g, zeta);
            d += t;
            zeta = fmaf(cz, g, zeta);
            unsigned int bits = __builtin_bit_cast(unsigned int, d) + 0x8000u;
            yo[r * 2 + half] = (unsigned short)(bits >> 16);
        }
    }
    #pragma unroll
    for (int j = 0; j < 16; ++j)
        ysb[(size_t)(bk * 16 + j) * P_SZ + p] = yo[j];
}

extern "C" void kernel_launch(void* const* d_in, const int* in_sizes, int n_in,
                              void* d_out, int out_size, void* d_ws, size_t ws_size,
                              hipStream_t stream) {
    const float* u     = (const float*)d_in[0];  // (L,H)
    const float* B     = (const float*)d_in[1];  // (P,H)
    const float* C     = (const float*)d_in[2];  // (H,P)
    const float* D     = (const float*)d_in[3];  // (H,)
    const float* W     = (const float*)d_in[4];  // (P,)
    const float* b     = (const float*)d_in[5];  // (P,)
    const float* c     = (const float*)d_in[6];  // (P,)
    const float* alpha = (const float*)d_in[7];  // (1,)
    const float* step  = (const float*)d_in[8];  // (1,)
    float* out = (float*)d_out;                  // (L,H)

    char* ws = (char*)d_ws;
    uint4*          Qpk    = (uint4*)ws;                                  // 64 MiB
    unsigned short* ysb    = (unsigned short*)(ws + ((size_t)64 << 20));  // 16 MiB
    unsigned short* ub     = (unsigned short*)(ws + ((size_t)80 << 20));  // 8 MiB
    float2*         states = (float2*)(ws + ((size_t)80 << 20));          // 4 MiB (reuses ub after GEMM1)
    unsigned short* Bb     = (unsigned short*)(ws + ((size_t)88 << 20));  // 1 MiB
    unsigned short* Cb     = (unsigned short*)(ws + ((size_t)89 << 20));  // 1 MiB

    cvt_f32_bf16<<<dim3(L_SZ * H_SZ / 4 / 256), dim3(256), 0, stream>>>(u, ub, L_SZ * H_SZ / 4);
    cvt_f32_bf16<<<dim3(P_SZ * H_SZ / 4 / 256), dim3(256), 0, stream>>>(B, Bb, P_SZ * H_SZ / 4);
    cvt_scale_bf16<<<dim3(H_SZ * P_SZ / 4 / 256), dim3(256), 0, stream>>>(C, W, Cb, H_SZ * P_SZ / 4);

    // GEMM1 + fused tanh/Q-coefficient epilogue: (u @ B^T) -> Qpk
    gemm_nt_bf16<1><<<dim3(L_SZ / BT, P_SZ / BT), dim3(256), 0, stream>>>(
        ub, Bb, nullptr, L_SZ, P_SZ, H_SZ, nullptr, nullptr,
        Qpk, W, b, c, alpha);

    // Phase A: coarse sequential scan -> block-start states (ub now dead)
    scan_coarse<<<dim3(P_SZ / 64), dim3(64), 0, stream>>>(Qpk, states, W, step);

    // Phase B: parallel fine scan -> ysb (bf16 del = W*y)
    scan_fine<<<dim3(512, P_SZ / 256), dim3(256), 0, stream>>>(Qpk, states, ysb, W, step);

    // GEMM2: out = ys @ (C/W)^T + D .* u
    gemm_nt_bf16<0><<<dim3(L_SZ / BT, H_SZ / BT), dim3(256), 0, stream>>>(
        ysb, Cb, out, L_SZ, H_SZ, P_SZ, D, u,
        nullptr, nullptr, nullptr, nullptr, nullptr);
}

// Round 6
// 97.112 us; speedup vs baseline: 4.6974x; 1.2717x over previous
//
#include <hip/hip_runtime.h>
#include <math.h>

#define L_SZ 8192
#define H_SZ 512
#define P_SZ 1024

using bf16x8 = __attribute__((ext_vector_type(8))) short;
using f32x4  = __attribute__((ext_vector_type(4))) float;
using us4    = __attribute__((ext_vector_type(4))) unsigned short;

__device__ __forceinline__ unsigned short f2bf_rtn(float f) {
    unsigned int x = __builtin_bit_cast(unsigned int, f);
    x += 0x7fffu + ((x >> 16) & 1u);
    return (unsigned short)(x >> 16);
}
__device__ __forceinline__ unsigned int pack_bf2(float lo, float hi) {
    return (unsigned int)f2bf_rtn(lo) | ((unsigned int)f2bf_rtn(hi) << 16);
}
__device__ __forceinline__ float fast_tanh(float x) {
    float e = __builtin_amdgcn_exp2f(x * 2.8853900817779268f); // 2*log2(e)
    return 1.0f - 2.0f * __builtin_amdgcn_rcpf(e + 1.0f);
}
__device__ __forceinline__ float fast_sigmoid(float x) {
    float e = __builtin_amdgcn_exp2f(-x * 1.4426950408889634f);
    return __builtin_amdgcn_rcpf(1.0f + e);
}

#define NU4 (L_SZ * H_SZ / 4)     // 1,048,576
#define NB4 (P_SZ * H_SZ / 4)     // 131,072
#define NC4 (H_SZ * P_SZ / 4)     // 131,072

// one fused conversion kernel: u->bf16, B->bf16, C/W->bf16
__global__ __launch_bounds__(256) void cvt_all(
    const float* __restrict__ u, const float* __restrict__ B,
    const float* __restrict__ C, const float* __restrict__ Wd,
    unsigned short* __restrict__ ub, unsigned short* __restrict__ Bb,
    unsigned short* __restrict__ Cb)
{
    int i = blockIdx.x * 256 + threadIdx.x;
    if (i < NU4) {
        float4 v = reinterpret_cast<const float4*>(u)[i];
        us4 o;
        o.x = f2bf_rtn(v.x); o.y = f2bf_rtn(v.y);
        o.z = f2bf_rtn(v.z); o.w = f2bf_rtn(v.w);
        reinterpret_cast<us4*>(ub)[i] = o;
    } else if (i < NU4 + NB4) {
        int j = i - NU4;
        float4 v = reinterpret_cast<const float4*>(B)[j];
        us4 o;
        o.x = f2bf_rtn(v.x); o.y = f2bf_rtn(v.y);
        o.z = f2bf_rtn(v.z); o.w = f2bf_rtn(v.w);
        reinterpret_cast<us4*>(Bb)[j] = o;
    } else {
        int j = i - NU4 - NB4;
        float4 v = reinterpret_cast<const float4*>(C)[j];
        int p0 = (j * 4) & (P_SZ - 1);
        float4 wv = *reinterpret_cast<const float4*>(&Wd[p0]);
        us4 o;
        o.x = f2bf_rtn(v.x / wv.x); o.y = f2bf_rtn(v.y / wv.y);
        o.z = f2bf_rtn(v.z / wv.z); o.w = f2bf_rtn(v.w / wv.w);
        reinterpret_cast<us4*>(Cb)[j] = o;
    }
}

__device__ __forceinline__ void gload_lds16(const void* g, void* l) {
    __builtin_amdgcn_global_load_lds(
        (const __attribute__((address_space(1))) unsigned int*)g,
        (__attribute__((address_space(3))) unsigned int*)l, 16, 0, 0);
}

#define BT  128
#define BKK 32

// NT bf16 MFMA GEMM.
// MODE 0: Cout[m][n] = acc + Dvec[n]*U[m][n]   (GEMM2)
// MODE 1: Q-coefficient epilogue (GEMM1): a = acc + b[n]; f = tanh(a);
//         emit packed bf16 {Q0,Q1,Q2,Q3} per (timestep, channel)
template <int MODE>
__global__ __launch_bounds__(256) void gemm_nt_bf16(
    const unsigned short* __restrict__ A,   // (M,K) bf16 row-major
    const unsigned short* __restrict__ Bm,  // (N,K) bf16 row-major
    float* __restrict__ Cout, int M, int N, int K,
    const float* __restrict__ Dvec, const float* __restrict__ U,
    uint4* __restrict__ Qpk,
    const float* __restrict__ Wd, const float* __restrict__ bv,
    const float* __restrict__ cvec, const float* __restrict__ alpha_p)
{
    __shared__ __align__(16) unsigned short As[BT * BKK];
    __shared__ __align__(16) unsigned short Bs[BT * BKK];
    const int tid  = threadIdx.x;
    const int wave = tid >> 6;
    const int lane = tid & 63;
    const int bm = blockIdx.x * BT;
    const int bn = blockIdx.y * BT;
    const int wm = (wave >> 1) * 64;
    const int wn = (wave & 1) * 64;

    const int srow = wave * 16 + (lane >> 2);
    const int scol = (lane & 3) * 8;
    const unsigned short* aptr0 = A  + (size_t)(bm + srow)      * K + scol;
    const unsigned short* aptr1 = A  + (size_t)(bm + 64 + srow) * K + scol;
    const unsigned short* bptr0 = Bm + (size_t)(bn + srow)      * K + scol;
    const unsigned short* bptr1 = Bm + (size_t)(bn + 64 + srow) * K + scol;
    unsigned short* asl0 = As + wave * 512;
    unsigned short* asl1 = As + 2048 + wave * 512;
    unsigned short* bsl0 = Bs + wave * 512;
    unsigned short* bsl1 = Bs + 2048 + wave * 512;

    const int frow = lane & 15;
    const int fk   = (lane >> 4) * 8;

    f32x4 acc[4][4];
    #pragma unroll
    for (int i = 0; i < 4; ++i)
        #pragma unroll
        for (int j = 0; j < 4; ++j)
            acc[i][j] = (f32x4){0.f, 0.f, 0.f, 0.f};

    for (int k0 = 0; k0 < K; k0 += BKK) {
        __syncthreads();
        gload_lds16(aptr0 + k0, asl0);
        gload_lds16(aptr1 + k0, asl1);
        gload_lds16(bptr0 + k0, bsl0);
        gload_lds16(bptr1 + k0, bsl1);
        __syncthreads();
        bf16x8 a[4], b[4];
        #pragma unroll
        for (int i = 0; i < 4; ++i) {
            a[i] = *reinterpret_cast<const bf16x8*>(&As[(wm + i * 16 + frow) * BKK + fk]);
            b[i] = *reinterpret_cast<const bf16x8*>(&Bs[(wn + i * 16 + frow) * BKK + fk]);
        }
        #pragma unroll
        for (int i = 0; i < 4; ++i)
            #pragma unroll
            for (int j = 0; j < 4; ++j)
                acc[i][j] = __builtin_amdgcn_mfma_f32_16x16x32_bf16(a[i], b[j], acc[i][j], 0, 0, 0);
    }

    const int crow = bm + wm + (lane >> 4) * 4;   // multiple of 4
    const int ccol = bn + wn + (lane & 15);

    if constexpr (MODE == 0) {
        #pragma unroll
        for (int i = 0; i < 4; ++i)
            #pragma unroll
            for (int j = 0; j < 4; ++j)
                #pragma unroll
                for (int r = 0; r < 4; ++r) {
                    int row = crow + i * 16 + r;
                    int col = ccol + j * 16;
                    float v = acc[i][j][r];
                    v = fmaf(Dvec[col], U[(size_t)row * N + col], v);
                    Cout[(size_t)row * N + col] = v;
                }
    } else {
        const float alpha = alpha_p[0];
        #pragma unroll
        for (int j = 0; j < 4; ++j) {
            const int col = ccol + j * 16;
            const float ce  = fast_sigmoid(fast_sigmoid(cvec[col]));
            const float ce3 = ce * (1.0f / 3.0f);
            const float alW = alpha / Wd[col];
            const float bb  = bv[col];
            #pragma unroll
            for (int i = 0; i < 4; ++i) {
                unsigned int w01[4], w23[4];
                #pragma unroll
                for (int r = 0; r < 4; ++r) {
                    float a  = acc[i][j][r] + bb;
                    float f  = fast_tanh(a);
                    float p1 = fmaf(-f, f, 1.0f);          // 1 - f^2
                    float q0 = ce * f;
                    float q1 = fmaf(ce, p1, alW);
                    float q2 = -q0 * p1;                    // -ce*f*(1-f^2)
                    float t3 = fmaf(-3.0f * f, f, 1.0f);    // 1 - 3f^2
                    float q3 = -ce3 * p1 * t3;              // -(ce/3)(1-f^2)(1-3f^2)
                    w01[r] = pack_bf2(q0, q1);
                    w23[r] = pack_bf2(q2, q3);
                }
                const int row0 = crow + i * 16;             // even
                size_t tp0 = (size_t)(row0 >> 1) * P_SZ + col;
                Qpk[tp0]        = make_uint4(w01[0], w23[0], w01[1], w23[1]);
                Qpk[tp0 + P_SZ] = make_uint4(w01[2], w23[2], w01[3], w23[3]);
            }
        }
    }
}

// ---------------- Phase A: coarse sequential scan (512 Verlet steps) -------
// Direct strided register loads from Qpk (uint2 = Q-words of fine step 16k),
// 4 batches x 8 steps in flight, counted vmcnt fences. No LDS.
//   g = Q0+Q1*d+Q2*d^2+Q3*d^3 ; zeta += 8cz*(gprev+g) ;
//   states <- (d, zeta) ; d += 16*zeta + 128*cz*g.
// states packed as float4 = two consecutive block-start states.

__global__ __launch_bounds__(64, 1) void scan_coarse(
    const uint2* __restrict__ Qpk2, float4* __restrict__ states4,
    const float* __restrict__ Wd, const float* __restrict__ step_p)
{
    const int lane = threadIdx.x;
    const int p = blockIdx.x * 64 + lane;
    const float W  = Wd[p];
    const float st = step_p[0];
    const float cz    = -W * st * st;
    const float cz8   = 8.0f * cz;
    const float cz128 = 128.0f * cz;

    const uint2* qp = Qpk2 + 2 * p;   // coarse step s -> qp[(size_t)16*s*P_SZ]
    float4* sp = states4 + p;         // pair q -> sp[(size_t)q*P_SZ]

    float d = 0.f, zeta = 0.f, gprev = 0.f;
    uint2 qb0[8], qb1[8], qb2[8], qb3[8];

#define LOADB(B, K) { _Pragma("unroll")                                      \
    for (int j = 0; j < 8; ++j)                                              \
        B[j] = qp[(size_t)((K) * 8 + j) * 16 * P_SZ]; }

#define CSTEP(wrd, dout, zout) {                                             \
    float Q0 = __builtin_bit_cast(float, (wrd).x << 16);                     \
    float Q1 = __builtin_bit_cast(float, (wrd).x);                           \
    float Q2 = __builtin_bit_cast(float, (wrd).y << 16);                     \
    float Q3 = __builtin_bit_cast(float, (wrd).y);                           \
    float h = fmaf(Q3, d, Q2); h = fmaf(h, d, Q1);                           \
    float g = fmaf(h, d, Q0);                                                \
    zeta = fmaf(cz8, gprev + g, zeta);                                       \
    dout = d; zout = zeta;                                                   \
    d = fmaf(cz128, g, fmaf(16.0f, zeta, d));                                \
    gprev = g; }

#define COMPB(B, K) { _Pragma("unroll")                                      \
    for (int q = 0; q < 4; ++q) {                                            \
        float d0, z0, d1, z1;                                                \
        CSTEP(B[2 * q],     d0, z0);                                         \
        CSTEP(B[2 * q + 1], d1, z1);                                         \
        sp[(size_t)((K) * 4 + q) * P_SZ] = make_float4(d0, z0, d1, z1); } }

#define WAITI(N) asm volatile("s_waitcnt vmcnt(" #N ")" ::: "memory")

    LOADB(qb0, 0); LOADB(qb1, 1); LOADB(qb2, 2); LOADB(qb3, 3);

    WAITI(24); COMPB(qb0, 0); LOADB(qb0, 4);
    WAITI(28); COMPB(qb1, 1); LOADB(qb1, 5);
    WAITI(32); COMPB(qb2, 2); LOADB(qb2, 6);
    WAITI(36); COMPB(qb3, 3); LOADB(qb3, 7);

    for (int k = 4; k < 60; k += 4) {
        WAITI(36); COMPB(qb0, k);     LOADB(qb0, k + 4);
        WAITI(36); COMPB(qb1, k + 1); LOADB(qb1, k + 5);
        WAITI(36); COMPB(qb2, k + 2); LOADB(qb2, k + 6);
        WAITI(36); COMPB(qb3, k + 3); LOADB(qb3, k + 7);
    }

    WAITI(36); COMPB(qb0, 60);
    WAITI(28); COMPB(qb1, 61);
    WAITI(20); COMPB(qb2, 62);
    WAITI(12); COMPB(qb3, 63);

#undef LOADB
#undef CSTEP
#undef COMPB
#undef WAITI
}

// ---------------- Phase B: parallel fine scan (exact cubic recurrence) -----
__global__ __launch_bounds__(256) void scan_fine(
    const uint4* __restrict__ Qpk, const float4* __restrict__ states4,
    unsigned short* __restrict__ ysb,
    const float* __restrict__ Wd, const float* __restrict__ step_p)
{
    const int p  = blockIdx.y * 256 + threadIdx.x;
    const int bk = blockIdx.x;                    // time-block 0..511
    const float W  = Wd[p];
    const float st = step_p[0];
    const float cz = -W * st * st;
    const float ch = 0.5f * cz;

    float4 s4 = states4[(size_t)(bk >> 1) * P_SZ + p];
    float d    = (bk & 1) ? s4.z : s4.x;
    float zeta = (bk & 1) ? s4.w : s4.y;

    uint4 q[8];
    #pragma unroll
    for (int r = 0; r < 8; ++r)
        q[r] = Qpk[(size_t)(bk * 8 + r) * P_SZ + p];

    unsigned short yo[16];
    #pragma unroll
    for (int r = 0; r < 8; ++r) {
        #pragma unroll
        for (int half = 0; half < 2; ++half) {
            unsigned int w01 = half ? q[r].z : q[r].x;
            unsigned int w23 = half ? q[r].w : q[r].y;
            float Q0 = __builtin_bit_cast(float, w01 << 16);
            float Q1 = __builtin_bit_cast(float, w01);
            float Q2 = __builtin_bit_cast(float, w23 << 16);
            float Q3 = __builtin_bit_cast(float, w23);
            float h = fmaf(Q3, d, Q2);
            h = fmaf(h, d, Q1);
            float g = fmaf(h, d, Q0);
            float t = fmaf(ch, g, zeta);
            d += t;
            zeta = fmaf(cz, g, zeta);
            unsigned int bits = __builtin_bit_cast(unsigned int, d) + 0x8000u;
            yo[r * 2 + half] = (unsigned short)(bits >> 16);
        }
    }
    #pragma unroll
    for (int j = 0; j < 16; ++j)
        ysb[(size_t)(bk * 16 + j) * P_SZ + p] = yo[j];
}

extern "C" void kernel_launch(void* const* d_in, const int* in_sizes, int n_in,
                              void* d_out, int out_size, void* d_ws, size_t ws_size,
                              hipStream_t stream) {
    const float* u     = (const float*)d_in[0];  // (L,H)
    const float* B     = (const float*)d_in[1];  // (P,H)
    const float* C     = (const float*)d_in[2];  // (H,P)
    const float* D     = (const float*)d_in[3];  // (H,)
    const float* W     = (const float*)d_in[4];  // (P,)
    const float* b     = (const float*)d_in[5];  // (P,)
    const float* c     = (const float*)d_in[6];  // (P,)
    const float* alpha = (const float*)d_in[7];  // (1,)
    const float* step  = (const float*)d_in[8];  // (1,)
    float* out = (float*)d_out;                  // (L,H)

    char* ws = (char*)d_ws;
    uint4*          Qpk    = (uint4*)ws;                                  // 64 MiB
    unsigned short* ysb    = (unsigned short*)(ws + ((size_t)64 << 20));  // 16 MiB
    unsigned short* ub     = (unsigned short*)(ws + ((size_t)80 << 20));  // 8 MiB
    float4*         states = (float4*)(ws + ((size_t)80 << 20));          // 4 MiB (reuses ub after GEMM1)
    unsigned short* Bb     = (unsigned short*)(ws + ((size_t)88 << 20));  // 1 MiB
    unsigned short* Cb     = (unsigned short*)(ws + ((size_t)89 << 20));  // 1 MiB

    cvt_all<<<dim3((NU4 + NB4 + NC4) / 256), dim3(256), 0, stream>>>(
        u, B, C, W, ub, Bb, Cb);

    // GEMM1 + fused tanh/Q-coefficient epilogue: (u @ B^T) -> Qpk
    gemm_nt_bf16<1><<<dim3(L_SZ / BT, P_SZ / BT), dim3(256), 0, stream>>>(
        ub, Bb, nullptr, L_SZ, P_SZ, H_SZ, nullptr, nullptr,
        Qpk, W, b, c, alpha);

    // Phase A: coarse sequential scan -> block-start states (ub now dead)
    scan_coarse<<<dim3(P_SZ / 64), dim3(64), 0, stream>>>(
        (const uint2*)Qpk, states, W, step);

    // Phase B: parallel fine scan -> ysb (bf16 del = W*y)
    scan_fine<<<dim3(512, P_SZ / 256), dim3(256), 0, stream>>>(
        Qpk, states, ysb, W, step);

    // GEMM2: out = ys @ (C/W)^T + D .* u
    gemm_nt_bf16<0><<<dim3(L_SZ / BT, H_SZ / BT), dim3(256), 0, stream>>>(
        ysb, Cb, out, L_SZ, H_SZ, P_SZ, D, u,
        nullptr, nullptr, nullptr, nullptr, nullptr);
}

// Round 7
// 84.962 us; speedup vs baseline: 5.3692x; 1.1430x over previous
//
#include <hip/hip_runtime.h>
#include <math.h>

#define L_SZ 8192
#define H_SZ 512
#define P_SZ 1024

using bf16x8 = __attribute__((ext_vector_type(8))) short;
using f32x4  = __attribute__((ext_vector_type(4))) float;
using us4    = __attribute__((ext_vector_type(4))) unsigned short;

__device__ __forceinline__ unsigned short f2bf_rtn(float f) {
    unsigned int x = __builtin_bit_cast(unsigned int, f);
    x += 0x7fffu + ((x >> 16) & 1u);
    return (unsigned short)(x >> 16);
}
__device__ __forceinline__ unsigned int pack_bf2(float lo, float hi) {
    return (unsigned int)f2bf_rtn(lo) | ((unsigned int)f2bf_rtn(hi) << 16);
}
__device__ __forceinline__ float fast_tanh(float x) {
    float e = __builtin_amdgcn_exp2f(x * 2.8853900817779268f); // 2*log2(e)
    return 1.0f - 2.0f * __builtin_amdgcn_rcpf(e + 1.0f);
}
__device__ __forceinline__ float fast_sigmoid(float x) {
    float e = __builtin_amdgcn_exp2f(-x * 1.4426950408889634f);
    return __builtin_amdgcn_rcpf(1.0f + e);
}

#define NU4 (L_SZ * H_SZ / 4)     // 1,048,576
#define NB4 (P_SZ * H_SZ / 4)     // 131,072
#define NC4 (H_SZ * P_SZ / 4)     // 131,072

// one fused conversion kernel: u->bf16, B->bf16, C/W->bf16
__global__ __launch_bounds__(256) void cvt_all(
    const float* __restrict__ u, const float* __restrict__ B,
    const float* __restrict__ C, const float* __restrict__ Wd,
    unsigned short* __restrict__ ub, unsigned short* __restrict__ Bb,
    unsigned short* __restrict__ Cb)
{
    int i = blockIdx.x * 256 + threadIdx.x;
    if (i < NU4) {
        float4 v = reinterpret_cast<const float4*>(u)[i];
        us4 o;
        o.x = f2bf_rtn(v.x); o.y = f2bf_rtn(v.y);
        o.z = f2bf_rtn(v.z); o.w = f2bf_rtn(v.w);
        reinterpret_cast<us4*>(ub)[i] = o;
    } else if (i < NU4 + NB4) {
        int j = i - NU4;
        float4 v = reinterpret_cast<const float4*>(B)[j];
        us4 o;
        o.x = f2bf_rtn(v.x); o.y = f2bf_rtn(v.y);
        o.z = f2bf_rtn(v.z); o.w = f2bf_rtn(v.w);
        reinterpret_cast<us4*>(Bb)[j] = o;
    } else {
        int j = i - NU4 - NB4;
        float4 v = reinterpret_cast<const float4*>(C)[j];
        int p0 = (j * 4) & (P_SZ - 1);
        float4 wv = *reinterpret_cast<const float4*>(&Wd[p0]);
        us4 o;
        o.x = f2bf_rtn(v.x / wv.x); o.y = f2bf_rtn(v.y / wv.y);
        o.z = f2bf_rtn(v.z / wv.z); o.w = f2bf_rtn(v.w / wv.w);
        reinterpret_cast<us4*>(Cb)[j] = o;
    }
}

__device__ __forceinline__ void gload_lds16(const void* g, void* l) {
    __builtin_amdgcn_global_load_lds(
        (const __attribute__((address_space(1))) unsigned int*)g,
        (__attribute__((address_space(3))) unsigned int*)l, 16, 0, 0);
}

#define BT  128
#define BKK 32

// NT bf16 MFMA GEMM.
// MODE 0: Cout[m][n] = acc + Dvec[n]*U[m][n]                      (GEMM2)
// MODE 1: ab[l][n] = bf16(acc + b[n]) for all elements, plus cubic
//         tanh-Taylor coeffs Qc[l/16][n] for block-start rows      (GEMM1)
template <int MODE>
__global__ __launch_bounds__(256) void gemm_nt_bf16(
    const unsigned short* __restrict__ A,   // (M,K) bf16 row-major
    const unsigned short* __restrict__ Bm,  // (N,K) bf16 row-major
    float* __restrict__ Cout, int M, int N, int K,
    const float* __restrict__ Dvec, const float* __restrict__ U,
    unsigned short* __restrict__ ab, uint2* __restrict__ Qc,
    const float* __restrict__ Wd, const float* __restrict__ bv,
    const float* __restrict__ cvec, const float* __restrict__ alpha_p)
{
    __shared__ __align__(16) unsigned short As[BT * BKK];
    __shared__ __align__(16) unsigned short Bs[BT * BKK];
    const int tid  = threadIdx.x;
    const int wave = tid >> 6;
    const int lane = tid & 63;
    const int bm = blockIdx.x * BT;
    const int bn = blockIdx.y * BT;
    const int wm = (wave >> 1) * 64;
    const int wn = (wave & 1) * 64;

    const int srow = wave * 16 + (lane >> 2);
    const int scol = (lane & 3) * 8;
    const unsigned short* aptr0 = A  + (size_t)(bm + srow)      * K + scol;
    const unsigned short* aptr1 = A  + (size_t)(bm + 64 + srow) * K + scol;
    const unsigned short* bptr0 = Bm + (size_t)(bn + srow)      * K + scol;
    const unsigned short* bptr1 = Bm + (size_t)(bn + 64 + srow) * K + scol;
    unsigned short* asl0 = As + wave * 512;
    unsigned short* asl1 = As + 2048 + wave * 512;
    unsigned short* bsl0 = Bs + wave * 512;
    unsigned short* bsl1 = Bs + 2048 + wave * 512;

    const int frow = lane & 15;
    const int fk   = (lane >> 4) * 8;

    f32x4 acc[4][4];
    #pragma unroll
    for (int i = 0; i < 4; ++i)
        #pragma unroll
        for (int j = 0; j < 4; ++j)
            acc[i][j] = (f32x4){0.f, 0.f, 0.f, 0.f};

    for (int k0 = 0; k0 < K; k0 += BKK) {
        __syncthreads();
        gload_lds16(aptr0 + k0, asl0);
        gload_lds16(aptr1 + k0, asl1);
        gload_lds16(bptr0 + k0, bsl0);
        gload_lds16(bptr1 + k0, bsl1);
        __syncthreads();
        bf16x8 a[4], b[4];
        #pragma unroll
        for (int i = 0; i < 4; ++i) {
            a[i] = *reinterpret_cast<const bf16x8*>(&As[(wm + i * 16 + frow) * BKK + fk]);
            b[i] = *reinterpret_cast<const bf16x8*>(&Bs[(wn + i * 16 + frow) * BKK + fk]);
        }
        #pragma unroll
        for (int i = 0; i < 4; ++i)
            #pragma unroll
            for (int j = 0; j < 4; ++j)
                acc[i][j] = __builtin_amdgcn_mfma_f32_16x16x32_bf16(a[i], b[j], acc[i][j], 0, 0, 0);
    }

    const int crow = bm + wm + (lane >> 4) * 4;   // multiple of 4
    const int ccol = bn + wn + (lane & 15);

    if constexpr (MODE == 0) {
        #pragma unroll
        for (int i = 0; i < 4; ++i)
            #pragma unroll
            for (int j = 0; j < 4; ++j)
                #pragma unroll
                for (int r = 0; r < 4; ++r) {
                    int row = crow + i * 16 + r;
                    int col = ccol + j * 16;
                    float v = acc[i][j][r];
                    v = fmaf(Dvec[col], U[(size_t)row * N + col], v);
                    Cout[(size_t)row * N + col] = v;
                }
    } else {
        // all lanes: a = acc + b[col] -> bf16 ab[row][col]
        #pragma unroll
        for (int j = 0; j < 4; ++j) {
            const int col = ccol + j * 16;
            const float bb = bv[col];
            #pragma unroll
            for (int i = 0; i < 4; ++i)
                #pragma unroll
                for (int r = 0; r < 4; ++r) {
                    int row = crow + i * 16 + r;
                    ab[(size_t)row * N + col] = f2bf_rtn(acc[i][j][r] + bb);
                }
        }
        // lanes 0-15 (crow = bm+wm, r=0): block-start rows (row%16==0) ->
        // cubic coeffs of g(d) = alW*d + ce*tanh(d + a) around d=0
        if (lane < 16) {
            const float alpha = alpha_p[0];
            #pragma unroll
            for (int j = 0; j < 4; ++j) {
                const int col = ccol + j * 16;
                const float ce  = fast_sigmoid(fast_sigmoid(cvec[col]));
                const float ce3 = ce * (1.0f / 3.0f);
                const float alW = alpha / Wd[col];
                const float bb  = bv[col];
                #pragma unroll
                for (int i = 0; i < 4; ++i) {
                    float a  = acc[i][j][0] + bb;           // row = crow+i*16
                    float f  = fast_tanh(a);
                    float p1 = fmaf(-f, f, 1.0f);           // 1 - f^2
                    float q0 = ce * f;
                    float q1 = fmaf(ce, p1, alW);
                    float q2 = -q0 * p1;                    // -ce*f*(1-f^2)
                    float t3 = fmaf(-3.0f * f, f, 1.0f);    // 1 - 3f^2
                    float q3 = -ce3 * p1 * t3;              // -(ce/3)(1-f^2)(1-3f^2)
                    int kq = (crow + i * 16) >> 4;
                    Qc[(size_t)kq * P_SZ + col] =
                        make_uint2(pack_bf2(q0, q1), pack_bf2(q2, q3));
                }
            }
        }
    }
}

// ---------------- Phase A: coarse sequential scan (512 Verlet steps) -------
// Direct register loads from compact Qc[512][1024] (uint2 per coarse step),
// 4 batches x 8 steps in flight, counted vmcnt fences. No LDS.
//   g = Q0+Q1*d+Q2*d^2+Q3*d^3 ; zeta += 8cz*(gprev+g) ;
//   states <- (d, zeta) ; d += 16*zeta + 128*cz*g.
// states packed as float4 = two consecutive block-start states.

__global__ __launch_bounds__(64, 1) void scan_coarse(
    const uint2* __restrict__ Qc, float4* __restrict__ states4,
    const float* __restrict__ Wd, const float* __restrict__ step_p)
{
    const int lane = threadIdx.x;
    const int p = blockIdx.x * 64 + lane;
    const float W  = Wd[p];
    const float st = step_p[0];
    const float cz    = -W * st * st;
    const float cz8   = 8.0f * cz;
    const float cz128 = 128.0f * cz;

    const uint2* qp = Qc + p;         // coarse step s -> qp[s * P_SZ]
    float4* sp = states4 + p;         // pair q -> sp[q * P_SZ]

    float d = 0.f, zeta = 0.f, gprev = 0.f;
    uint2 qb0[8], qb1[8], qb2[8], qb3[8];

#define LOADB(B, K) { _Pragma("unroll")                                      \
    for (int j = 0; j < 8; ++j)                                              \
        B[j] = qp[(size_t)((K) * 8 + j) * P_SZ]; }

#define CSTEP(wrd, dout, zout) {                                             \
    float Q0 = __builtin_bit_cast(float, (wrd).x << 16);                     \
    float Q1 = __builtin_bit_cast(float, (wrd).x);                           \
    float Q2 = __builtin_bit_cast(float, (wrd).y << 16);                     \
    float Q3 = __builtin_bit_cast(float, (wrd).y);                           \
    float h = fmaf(Q3, d, Q2); h = fmaf(h, d, Q1);                           \
    float g = fmaf(h, d, Q0);                                                \
    zeta = fmaf(cz8, gprev + g, zeta);                                       \
    dout = d; zout = zeta;                                                   \
    d = fmaf(cz128, g, fmaf(16.0f, zeta, d));                                \
    gprev = g; }

#define COMPB(B, K) { _Pragma("unroll")                                      \
    for (int q = 0; q < 4; ++q) {                                            \
        float d0, z0, d1, z1;                                                \
        CSTEP(B[2 * q],     d0, z0);                                         \
        CSTEP(B[2 * q + 1], d1, z1);                                         \
        sp[(size_t)((K) * 4 + q) * P_SZ] = make_float4(d0, z0, d1, z1); } }

#define WAITI(N) asm volatile("s_waitcnt vmcnt(" #N ")" ::: "memory")

    LOADB(qb0, 0); LOADB(qb1, 1); LOADB(qb2, 2); LOADB(qb3, 3);

    WAITI(24); COMPB(qb0, 0); LOADB(qb0, 4);
    WAITI(28); COMPB(qb1, 1); LOADB(qb1, 5);
    WAITI(32); COMPB(qb2, 2); LOADB(qb2, 6);
    WAITI(36); COMPB(qb3, 3); LOADB(qb3, 7);

    for (int k = 4; k < 60; k += 4) {
        WAITI(36); COMPB(qb0, k);     LOADB(qb0, k + 4);
        WAITI(36); COMPB(qb1, k + 1); LOADB(qb1, k + 5);
        WAITI(36); COMPB(qb2, k + 2); LOADB(qb2, k + 6);
        WAITI(36); COMPB(qb3, k + 3); LOADB(qb3, k + 7);
    }

    WAITI(36); COMPB(qb0, 60);
    WAITI(28); COMPB(qb1, 61);
    WAITI(20); COMPB(qb2, 62);
    WAITI(12); COMPB(qb3, 63);

#undef LOADB
#undef CSTEP
#undef COMPB
#undef WAITI
}

// ---------------- Phase B: parallel fine scan (EXACT recurrence) -----------
// 512 time-blocks x 1024 channels; 16 exact leapfrog steps from the coarse
// state, evaluating tanh directly (throughput-parallel, transcendentals ok):
//   g = alW*d + ce*tanh(d + a_t); d += ch*g + zeta; zeta += cz*g.

__global__ __launch_bounds__(256) void scan_fine(
    const unsigned short* __restrict__ ab, const float4* __restrict__ states4,
    unsigned short* __restrict__ ysb,
    const float* __restrict__ Wd, const float* __restrict__ cvec,
    const float* __restrict__ alpha_p, const float* __restrict__ step_p)
{
    const int p  = blockIdx.y * 256 + threadIdx.x;
    const int bk = blockIdx.x;                    // time-block 0..511
    const float W  = Wd[p];
    const float st = step_p[0];
    const float cz = -W * st * st;
    const float ch = 0.5f * cz;
    const float ce = fast_sigmoid(fast_sigmoid(cvec[p]));
    const float alW = alpha_p[0] / W;
    const float kk = 2.8853900817779268f;         // 2*log2(e)

    float4 s4 = states4[(size_t)(bk >> 1) * P_SZ + p];
    float d    = (bk & 1) ? s4.z : s4.x;
    float zeta = (bk & 1) ? s4.w : s4.y;

    float a[16];
    #pragma unroll
    for (int j = 0; j < 16; ++j) {
        unsigned int w = ab[(size_t)(bk * 16 + j) * P_SZ + p];
        a[j] = __builtin_bit_cast(float, w << 16);
    }

    unsigned short yo[16];
    #pragma unroll
    for (int j = 0; j < 16; ++j) {
        float e  = __builtin_amdgcn_exp2f(kk * (d + a[j]));
        float r  = __builtin_amdgcn_rcpf(e + 1.0f);
        float th = fmaf(-2.0f, r, 1.0f);          // tanh(d + a)
        float g  = fmaf(alW, d, ce * th);
        float t  = fmaf(ch, g, zeta);
        d += t;
        zeta = fmaf(cz, g, zeta);
        unsigned int bits = __builtin_bit_cast(unsigned int, d) + 0x8000u;
        yo[j] = (unsigned short)(bits >> 16);
    }
    #pragma unroll
    for (int j = 0; j < 16; ++j)
        ysb[(size_t)(bk * 16 + j) * P_SZ + p] = yo[j];
}

extern "C" void kernel_launch(void* const* d_in, const int* in_sizes, int n_in,
                              void* d_out, int out_size, void* d_ws, size_t ws_size,
                              hipStream_t stream) {
    const float* u     = (const float*)d_in[0];  // (L,H)
    const float* B     = (const float*)d_in[1];  // (P,H)
    const float* C     = (const float*)d_in[2];  // (H,P)
    const float* D     = (const float*)d_in[3];  // (H,)
    const float* W     = (const float*)d_in[4];  // (P,)
    const float* b     = (const float*)d_in[5];  // (P,)
    const float* c     = (const float*)d_in[6];  // (P,)
    const float* alpha = (const float*)d_in[7];  // (1,)
    const float* step  = (const float*)d_in[8];  // (1,)
    float* out = (float*)d_out;                  // (L,H)

    char* ws = (char*)d_ws;
    unsigned short* ab     = (unsigned short*)ws;                          // 16 MiB
    unsigned short* ysb    = (unsigned short*)(ws + ((size_t)16 << 20));   // 16 MiB
    uint2*          Qc     = (uint2*)(ws + ((size_t)32 << 20));            // 4 MiB
    float4*         states = (float4*)(ws + ((size_t)36 << 20));           // 4 MiB
    unsigned short* ub     = (unsigned short*)(ws + ((size_t)40 << 20));   // 8 MiB
    unsigned short* Bb     = (unsigned short*)(ws + ((size_t)48 << 20));   // 1 MiB
    unsigned short* Cb     = (unsigned short*)(ws + ((size_t)49 << 20));   // 1 MiB

    cvt_all<<<dim3((NU4 + NB4 + NC4) / 256), dim3(256), 0, stream>>>(
        u, B, C, W, ub, Bb, Cb);

    // GEMM1 + epilogue: ab = bf16(u@B^T + b), Qc cubic coeffs @ block starts
    gemm_nt_bf16<1><<<dim3(L_SZ / BT, P_SZ / BT), dim3(256), 0, stream>>>(
        ub, Bb, nullptr, L_SZ, P_SZ, H_SZ, nullptr, nullptr,
        ab, Qc, W, b, c, alpha);

    // Phase A: coarse sequential scan -> block-start states
    scan_coarse<<<dim3(P_SZ / 64), dim3(64), 0, stream>>>(
        Qc, states, W, step);

    // Phase B: parallel fine scan (exact tanh recurrence) -> ysb
    scan_fine<<<dim3(512, P_SZ / 256), dim3(256), 0, stream>>>(
        ab, states, ysb, W, c, alpha, step);

    // GEMM2: out = ys @ (C/W)^T + D .* u
    gemm_nt_bf16<0><<<dim3(L_SZ / BT, H_SZ / BT), dim3(256), 0, stream>>>(
        ysb, Cb, out, L_SZ, H_SZ, P_SZ, D, u,
        nullptr, nullptr, nullptr, nullptr, nullptr, nullptr);
}

// Round 8
// 74.629 us; speedup vs baseline: 6.1126x; 1.1385x over previous
//
#include <hip/hip_runtime.h>
#include <math.h>

#define L_SZ 8192
#define H_SZ 512
#define P_SZ 1024

using bf16x8 = __attribute__((ext_vector_type(8))) short;
using f32x4  = __attribute__((ext_vector_type(4))) float;
using us4    = __attribute__((ext_vector_type(4))) unsigned short;

__device__ __forceinline__ unsigned short f2bf_rtn(float f) {
    unsigned int x = __builtin_bit_cast(unsigned int, f);
    x += 0x7fffu + ((x >> 16) & 1u);
    return (unsigned short)(x >> 16);
}
__device__ __forceinline__ unsigned int pack_bf2(float lo, float hi) {
    return (unsigned int)f2bf_rtn(lo) | ((unsigned int)f2bf_rtn(hi) << 16);
}
__device__ __forceinline__ float fast_tanh(float x) {
    float e = __builtin_amdgcn_exp2f(x * 2.8853900817779268f); // 2*log2(e)
    return 1.0f - 2.0f * __builtin_amdgcn_rcpf(e + 1.0f);
}
__device__ __forceinline__ float fast_sigmoid(float x) {
    float e = __builtin_amdgcn_exp2f(-x * 1.4426950408889634f);
    return __builtin_amdgcn_rcpf(1.0f + e);
}

#define NU4 (L_SZ * H_SZ / 4)     // 1,048,576
#define NB4 (P_SZ * H_SZ / 4)     // 131,072
#define NC4 (H_SZ * P_SZ / 4)     // 131,072

// one fused conversion kernel: u->bf16, B->bf16, C/W->bf16
__global__ __launch_bounds__(256) void cvt_all(
    const float* __restrict__ u, const float* __restrict__ B,
    const float* __restrict__ C, const float* __restrict__ Wd,
    unsigned short* __restrict__ ub, unsigned short* __restrict__ Bb,
    unsigned short* __restrict__ Cb)
{
    int i = blockIdx.x * 256 + threadIdx.x;
    if (i < NU4) {
        float4 v = reinterpret_cast<const float4*>(u)[i];
        us4 o;
        o.x = f2bf_rtn(v.x); o.y = f2bf_rtn(v.y);
        o.z = f2bf_rtn(v.z); o.w = f2bf_rtn(v.w);
        reinterpret_cast<us4*>(ub)[i] = o;
    } else if (i < NU4 + NB4) {
        int j = i - NU4;
        float4 v = reinterpret_cast<const float4*>(B)[j];
        us4 o;
        o.x = f2bf_rtn(v.x); o.y = f2bf_rtn(v.y);
        o.z = f2bf_rtn(v.z); o.w = f2bf_rtn(v.w);
        reinterpret_cast<us4*>(Bb)[j] = o;
    } else {
        int j = i - NU4 - NB4;
        float4 v = reinterpret_cast<const float4*>(C)[j];
        int p0 = (j * 4) & (P_SZ - 1);
        float4 wv = *reinterpret_cast<const float4*>(&Wd[p0]);
        us4 o;
        o.x = f2bf_rtn(v.x / wv.x); o.y = f2bf_rtn(v.y / wv.y);
        o.z = f2bf_rtn(v.z / wv.z); o.w = f2bf_rtn(v.w / wv.w);
        reinterpret_cast<us4*>(Cb)[j] = o;
    }
}

__device__ __forceinline__ void gload_lds16(const void* g, void* l) {
    __builtin_amdgcn_global_load_lds(
        (const __attribute__((address_space(1))) unsigned int*)g,
        (__attribute__((address_space(3))) unsigned int*)l, 16, 0, 0);
}

// ---------------- NT bf16 MFMA GEMM, BK=64, XOR-swizzled LDS ---------------
// LDS layout: combined [BM+BN rows][64 cols bf16] (128 B/row), linear dest for
// global_load_lds; the st-swizzle (byte bits 4-6 ^= (row&7)<<4) is realized by
// pre-swizzling the per-lane GLOBAL source column and XORing the read address
// (rule #21: both-sides-or-neither).  Frag reads then hit 8 banks x 2 rows
// (2-way = free) instead of the old 8-way conflict.
// MODE 0: Cout[m][n] = acc + Dvec[n]*U[m][n]                       (GEMM2)
// MODE 1: ab = bf16(acc + b[n]) all elems; cubic coeffs Qc at rows%16==0 (GEMM1)
template <int BM, int BN, int MI, int MJ, int MODE>
__global__ __launch_bounds__(256) void gemm_nt(
    const unsigned short* __restrict__ A,   // (M,K) bf16 row-major
    const unsigned short* __restrict__ Bm,  // (N,K) bf16 row-major
    float* __restrict__ Cout, int M, int N, int K,
    const float* __restrict__ Dvec, const float* __restrict__ U,
    unsigned short* __restrict__ ab, uint2* __restrict__ Qc,
    const float* __restrict__ Wd, const float* __restrict__ bv,
    const float* __restrict__ cvec, const float* __restrict__ alpha_p)
{
    constexpr int BK = 64;
    constexpr int NROW = BM + BN;
    __shared__ __align__(16) unsigned short S[NROW * BK];
    const int tid  = threadIdx.x;
    const int wave = tid >> 6;
    const int lane = tid & 63;
    const int bm = blockIdx.x * BM;
    const int bn = blockIdx.y * BN;
    constexpr int WM = MI * 16, WN = MJ * 16;
    const int wm = (wave >> 1) * WM;
    const int wn = (wave & 1) * WN;

    // staging: call c covers combined rows c*8..c*8+7; lane -> row c*8+(lane>>3),
    // source col pre-swizzled: 8*((lane&7) ^ ((lane>>3)&7)) bf16 elems
    const int lrow = lane >> 3;
    const int lcol = ((lane & 7) ^ (lrow & 7)) * 8;

    const int frow = lane & 15;          // fragment row within 16
    const int fb   = (lane >> 4) * 16;   // fragment k-slot byte offset (0..48)

    f32x4 acc[MI][MJ];
    #pragma unroll
    for (int i = 0; i < MI; ++i)
        #pragma unroll
        for (int j = 0; j < MJ; ++j)
            acc[i][j] = (f32x4){0.f, 0.f, 0.f, 0.f};

    for (int k0 = 0; k0 < K; k0 += BK) {
        __syncthreads();
        #pragma unroll
        for (int cc = 0; cc < NROW / 32; ++cc) {
            const int c = cc * 4 + wave;
            const int row = c * 8 + lrow;
            const unsigned short* src = (row < BM)
                ? A  + (size_t)(bm + row) * K + k0 + lcol
                : Bm + (size_t)(bn + row - BM) * K + k0 + lcol;
            gload_lds16(src, (char*)S + c * 1024);
        }
        __syncthreads();
        #pragma unroll
        for (int kk = 0; kk < 2; ++kk) {
            bf16x8 a[MI], b[MJ];
            #pragma unroll
            for (int i = 0; i < MI; ++i) {
                int row = wm + i * 16 + frow;
                int byte = row * 128 + ((kk * 64 + fb) ^ ((row & 7) << 4));
                a[i] = *reinterpret_cast<const bf16x8*>((const char*)S + byte);
            }
            #pragma unroll
            for (int j = 0; j < MJ; ++j) {
                int row = BM + wn + j * 16 + frow;
                int byte = row * 128 + ((kk * 64 + fb) ^ ((row & 7) << 4));
                b[j] = *reinterpret_cast<const bf16x8*>((const char*)S + byte);
            }
            #pragma unroll
            for (int i = 0; i < MI; ++i)
                #pragma unroll
                for (int j = 0; j < MJ; ++j)
                    acc[i][j] = __builtin_amdgcn_mfma_f32_16x16x32_bf16(a[i], b[j], acc[i][j], 0, 0, 0);
        }
    }

    const int crow = bm + wm + (lane >> 4) * 4;   // multiple of 4
    const int ccol = bn + wn + (lane & 15);

    if constexpr (MODE == 0) {
        #pragma unroll
        for (int i = 0; i < MI; ++i)
            #pragma unroll
            for (int j = 0; j < MJ; ++j)
                #pragma unroll
                for (int r = 0; r < 4; ++r) {
                    int row = crow + i * 16 + r;
                    int col = ccol + j * 16;
                    float v = acc[i][j][r];
                    v = fmaf(Dvec[col], U[(size_t)row * N + col], v);
                    Cout[(size_t)row * N + col] = v;
                }
    } else {
        // all lanes: a = acc + b[col] -> bf16 ab[row][col]
        #pragma unroll
        for (int j = 0; j < MJ; ++j) {
            const int col = ccol + j * 16;
            const float bb = bv[col];
            #pragma unroll
            for (int i = 0; i < MI; ++i)
                #pragma unroll
                for (int r = 0; r < 4; ++r) {
                    int row = crow + i * 16 + r;
                    ab[(size_t)row * N + col] = f2bf_rtn(acc[i][j][r] + bb);
                }
        }
        // lanes 0-15 (r=0 rows are %16==0): cubic coeffs of
        // g(d) = alW*d + ce*tanh(d + a) around d=0
        if (lane < 16) {
            const float alpha = alpha_p[0];
            #pragma unroll
            for (int j = 0; j < MJ; ++j) {
                const int col = ccol + j * 16;
                const float ce  = fast_sigmoid(fast_sigmoid(cvec[col]));
                const float ce3 = ce * (1.0f / 3.0f);
                const float alW = alpha / Wd[col];
                const float bb  = bv[col];
                #pragma unroll
                for (int i = 0; i < MI; ++i) {
                    float a  = acc[i][j][0] + bb;           // row = crow+i*16
                    float f  = fast_tanh(a);
                    float p1 = fmaf(-f, f, 1.0f);           // 1 - f^2
                    float q0 = ce * f;
                    float q1 = fmaf(ce, p1, alW);
                    float q2 = -q0 * p1;                    // -ce*f*(1-f^2)
                    float t3 = fmaf(-3.0f * f, f, 1.0f);    // 1 - 3f^2
                    float q3 = -ce3 * p1 * t3;              // -(ce/3)(1-f^2)(1-3f^2)
                    int kq = (crow + i * 16) >> 4;
                    Qc[(size_t)kq * P_SZ + col] =
                        make_uint2(pack_bf2(q0, q1), pack_bf2(q2, q3));
                }
            }
        }
    }
}

// ---------------- Phase A: coarse sequential scan (512 Verlet steps) -------
__global__ __launch_bounds__(64, 1) void scan_coarse(
    const uint2* __restrict__ Qc, float4* __restrict__ states4,
    const float* __restrict__ Wd, const float* __restrict__ step_p)
{
    const int lane = threadIdx.x;
    const int p = blockIdx.x * 64 + lane;
    const float W  = Wd[p];
    const float st = step_p[0];
    const float cz    = -W * st * st;
    const float cz8   = 8.0f * cz;
    const float cz128 = 128.0f * cz;

    const uint2* qp = Qc + p;         // coarse step s -> qp[s * P_SZ]
    float4* sp = states4 + p;         // pair q -> sp[q * P_SZ]

    float d = 0.f, zeta = 0.f, gprev = 0.f;
    uint2 qb0[8], qb1[8], qb2[8], qb3[8];

#define LOADB(B, K) { _Pragma("unroll")                                      \
    for (int j = 0; j < 8; ++j)                                              \
        B[j] = qp[(size_t)((K) * 8 + j) * P_SZ]; }

#define CSTEP(wrd, dout, zout) {                                             \
    float Q0 = __builtin_bit_cast(float, (wrd).x << 16);                     \
    float Q1 = __builtin_bit_cast(float, (wrd).x);                           \
    float Q2 = __builtin_bit_cast(float, (wrd).y << 16);                     \
    float Q3 = __builtin_bit_cast(float, (wrd).y);                           \
    float h = fmaf(Q3, d, Q2); h = fmaf(h, d, Q1);                           \
    float g = fmaf(h, d, Q0);                                                \
    zeta = fmaf(cz8, gprev + g, zeta);                                       \
    dout = d; zout = zeta;                                                   \
    d = fmaf(cz128, g, fmaf(16.0f, zeta, d));                                \
    gprev = g; }

#define COMPB(B, K) { _Pragma("unroll")                                      \
    for (int q = 0; q < 4; ++q) {                                            \
        float d0, z0, d1, z1;                                                \
        CSTEP(B[2 * q],     d0, z0);                                         \
        CSTEP(B[2 * q + 1], d1, z1);                                         \
        sp[(size_t)((K) * 4 + q) * P_SZ] = make_float4(d0, z0, d1, z1); } }

#define WAITI(N) asm volatile("s_waitcnt vmcnt(" #N ")" ::: "memory")

    LOADB(qb0, 0); LOADB(qb1, 1); LOADB(qb2, 2); LOADB(qb3, 3);

    WAITI(24); COMPB(qb0, 0); LOADB(qb0, 4);
    WAITI(28); COMPB(qb1, 1); LOADB(qb1, 5);
    WAITI(32); COMPB(qb2, 2); LOADB(qb2, 6);
    WAITI(36); COMPB(qb3, 3); LOADB(qb3, 7);

    for (int k = 4; k < 60; k += 4) {
        WAITI(36); COMPB(qb0, k);     LOADB(qb0, k + 4);
        WAITI(36); COMPB(qb1, k + 1); LOADB(qb1, k + 5);
        WAITI(36); COMPB(qb2, k + 2); LOADB(qb2, k + 6);
        WAITI(36); COMPB(qb3, k + 3); LOADB(qb3, k + 7);
    }

    WAITI(36); COMPB(qb0, 60);
    WAITI(28); COMPB(qb1, 61);
    WAITI(20); COMPB(qb2, 62);
    WAITI(12); COMPB(qb3, 63);

#undef LOADB
#undef CSTEP
#undef COMPB
#undef WAITI
}

// ---------------- Phase B: parallel fine scan (EXACT recurrence) -----------
__global__ __launch_bounds__(256) void scan_fine(
    const unsigned short* __restrict__ ab, const float4* __restrict__ states4,
    unsigned short* __restrict__ ysb,
    const float* __restrict__ Wd, const float* __restrict__ cvec,
    const float* __restrict__ alpha_p, const float* __restrict__ step_p)
{
    const int p  = blockIdx.y * 256 + threadIdx.x;
    const int bk = blockIdx.x;                    // time-block 0..511
    const float W  = Wd[p];
    const float st = step_p[0];
    const float cz = -W * st * st;
    const float ch = 0.5f * cz;
    const float ce = fast_sigmoid(fast_sigmoid(cvec[p]));
    const float alW = alpha_p[0] / W;
    const float kk = 2.8853900817779268f;         // 2*log2(e)

    float4 s4 = states4[(size_t)(bk >> 1) * P_SZ + p];
    float d    = (bk & 1) ? s4.z : s4.x;
    float zeta = (bk & 1) ? s4.w : s4.y;

    float a[16];
    #pragma unroll
    for (int j = 0; j < 16; ++j) {
        unsigned int w = ab[(size_t)(bk * 16 + j) * P_SZ + p];
        a[j] = __builtin_bit_cast(float, w << 16);
    }

    unsigned short yo[16];
    #pragma unroll
    for (int j = 0; j < 16; ++j) {
        float e  = __builtin_amdgcn_exp2f(kk * (d + a[j]));
        float r  = __builtin_amdgcn_rcpf(e + 1.0f);
        float th = fmaf(-2.0f, r, 1.0f);          // tanh(d + a)
        float g  = fmaf(alW, d, ce * th);
        float t  = fmaf(ch, g, zeta);
        d += t;
        zeta = fmaf(cz, g, zeta);
        unsigned int bits = __builtin_bit_cast(unsigned int, d) + 0x8000u;
        yo[j] = (unsigned short)(bits >> 16);
    }
    #pragma unroll
    for (int j = 0; j < 16; ++j)
        ysb[(size_t)(bk * 16 + j) * P_SZ + p] = yo[j];
}

extern "C" void kernel_launch(void* const* d_in, const int* in_sizes, int n_in,
                              void* d_out, int out_size, void* d_ws, size_t ws_size,
                              hipStream_t stream) {
    const float* u     = (const float*)d_in[0];  // (L,H)
    const float* B     = (const float*)d_in[1];  // (P,H)
    const float* C     = (const float*)d_in[2];  // (H,P)
    const float* D     = (const float*)d_in[3];  // (H,)
    const float* W     = (const float*)d_in[4];  // (P,)
    const float* b     = (const float*)d_in[5];  // (P,)
    const float* c     = (const float*)d_in[6];  // (P,)
    const float* alpha = (const float*)d_in[7];  // (1,)
    const float* step  = (const float*)d_in[8];  // (1,)
    float* out = (float*)d_out;                  // (L,H)

    char* ws = (char*)d_ws;
    unsigned short* ab     = (unsigned short*)ws;                          // 16 MiB
    unsigned short* ysb    = (unsigned short*)(ws + ((size_t)16 << 20));   // 16 MiB
    uint2*          Qc     = (uint2*)(ws + ((size_t)32 << 20));            // 4 MiB
    float4*         states = (float4*)(ws + ((size_t)36 << 20));           // 4 MiB
    unsigned short* ub     = (unsigned short*)(ws + ((size_t)40 << 20));   // 8 MiB
    unsigned short* Bb     = (unsigned short*)(ws + ((size_t)48 << 20));   // 1 MiB
    unsigned short* Cb     = (unsigned short*)(ws + ((size_t)49 << 20));   // 1 MiB

    cvt_all<<<dim3((NU4 + NB4 + NC4) / 256), dim3(256), 0, stream>>>(
        u, B, C, W, ub, Bb, Cb);

    // GEMM1 + epilogue: ab = bf16(u@B^T + b), Qc cubic coeffs @ block starts
    gemm_nt<128, 128, 4, 4, 1><<<dim3(L_SZ / 128, P_SZ / 128), dim3(256), 0, stream>>>(
        ub, Bb, nullptr, L_SZ, P_SZ, H_SZ, nullptr, nullptr,
        ab, Qc, W, b, c, alpha);

    // Phase A: coarse sequential scan -> block-start states
    scan_coarse<<<dim3(P_SZ / 64), dim3(64), 0, stream>>>(
        Qc, states, W, step);

    // Phase B: parallel fine scan (exact tanh recurrence) -> ysb
    scan_fine<<<dim3(512, P_SZ / 256), dim3(256), 0, stream>>>(
        ab, states, ysb, W, c, alpha, step);

    // GEMM2: out = ys @ (C/W)^T + D .* u   (64x128 tile -> 512 blocks, 2/CU)
    gemm_nt<64, 128, 2, 4, 0><<<dim3(L_SZ / 64, H_SZ / 128), dim3(256), 0, stream>>>(
        ysb, Cb, out, L_SZ, H_SZ, P_SZ, D, u,
        nullptr, nullptr, nullptr, nullptr, nullptr, nullptr);
}